// Round 3
// baseline (688.635 us; speedup 1.0000x reference)
//
#include <hip/hip_runtime.h>
#include <hip/hip_bf16.h>
#include <cstdint>
#include <cstddef>

#define BATCH 8
#define CINC  64
#define HH    128
#define WWW   128
#define COUTC 128
#define KKC   9
#define KDIM  576   // KK*CIN, k = kk*64 + c
#define HWC   (HH*WWW)      // 16384
#define NPX   (BATCH*HWC)   // 131072

typedef float f32x4 __attribute__((ext_vector_type(4)));
typedef short bf16x8 __attribute__((ext_vector_type(8)));

static __device__ __forceinline__ unsigned short f2bf(float f){
    unsigned u = __builtin_bit_cast(unsigned, f);
    u += 0x7fffu + ((u >> 16) & 1u);
    return (unsigned short)(u >> 16);
}
static __device__ __forceinline__ float bf_lo(unsigned u){
    return __builtin_bit_cast(float, u << 16);
}
static __device__ __forceinline__ float bf_hi(unsigned u){
    return __builtin_bit_cast(float, u & 0xffff0000u);
}

// ---------------- K0: pack weights to bf16, k = kk*64+c, row-major [o][k] ----
__global__ __launch_bounds__(256) void prep_weights(
        const float* __restrict__ off_w, const float* __restrict__ mod_w,
        const float* __restrict__ reg_w,
        unsigned short* __restrict__ Wb, unsigned short* __restrict__ Wc)
{
    int idx = blockIdx.x * 256 + threadIdx.x;
    if (idx < COUTC * KDIM) {
        int o = idx / KDIM, k = idx % KDIM;
        int kk = k >> 6, c = k & 63;
        Wb[idx] = f2bf(reg_w[(o * CINC + c) * KKC + kk]);
    }
    int idx2 = idx - COUTC * KDIM;
    if (idx2 >= 0 && idx2 < 32 * KDIM) {
        int o = idx2 / KDIM, k = idx2 % KDIM;
        int kk = k >> 6, c = k & 63;
        float v = 0.f;
        if (o < 18)      v = off_w[(o * CINC + c) * KKC + kk];      // o = kk*2+d
        else if (o < 27) v = mod_w[((o - 18) * CINC + c) * KKC + kk];
        Wc[idx2] = f2bf(v);
    }
}

// ---------------- K1: 1x1 conv, NCHW f32 -> NHWC bf16 ----------------------
__global__ __launch_bounds__(256) void conv1x1(
        const float* __restrict__ x, const float* __restrict__ pre_w,
        const float* __restrict__ pre_b, unsigned short* __restrict__ xp)
{
    __shared__ float wlds[CINC * CINC];   // [ci][co]
    __shared__ float blds[CINC];
    int tid = threadIdx.x;
    for (int i = tid; i < CINC * CINC; i += 256) {
        int co = i >> 6, ci = i & 63;
        wlds[ci * 64 + co] = pre_w[i];    // pre_w[co][ci][1][1]
    }
    if (tid < CINC) blds[tid] = pre_b[tid];
    __syncthreads();

    int px = blockIdx.x * 256 + tid;
    int b = px >> 14, hw = px & 16383;
    float acc[CINC];
    #pragma unroll
    for (int co = 0; co < CINC; ++co) acc[co] = blds[co];
    for (int ci = 0; ci < CINC; ++ci) {
        float xv = x[(size_t)(b * CINC + ci) * HWC + hw];
        #pragma unroll
        for (int co = 0; co < CINC; ++co) acc[co] += xv * wlds[ci * 64 + co];
    }
    unsigned pk[32];
    #pragma unroll
    for (int j = 0; j < 32; ++j)
        pk[j] = (unsigned)f2bf(acc[2*j]) | ((unsigned)f2bf(acc[2*j+1]) << 16);
    uint4* dst = (uint4*)(xp + (size_t)px * 64);
    #pragma unroll
    for (int q = 0; q < 8; ++q)
        dst[q] = make_uint4(pk[4*q], pk[4*q+1], pk[4*q+2], pk[4*q+3]);
}

// ---------------- K2: offset/mask 3x3 conv -> coords[32][NPX] ---------------
// 1024 blocks x 256 threads (4 waves). XCD-swizzled so image k stays on XCD k.
__global__ __launch_bounds__(256) void offset_conv(
        const unsigned short* __restrict__ xp,
        const unsigned short* __restrict__ Wc,
        const float* __restrict__ off_b,
        const float* __restrict__ mod_b,
        float* __restrict__ coords)
{
    __shared__ uint4 WcL[32 * 73];   // pitch 73 uint4 = 584 shorts
    int tid = threadIdx.x;
    for (int j = tid; j < 32 * 72; j += 256) {
        int row = j / 72, c16 = j % 72;
        WcL[row * 73 + c16] = ((const uint4*)Wc)[j];
    }
    __syncthreads();
    const unsigned short* WcS = (const unsigned short*)WcL;

    const int lane = tid & 63;
    const int wv   = tid >> 6;
    const int l15  = lane & 15;
    const int l4   = lane >> 4;
    int bid = (int)blockIdx.x;
    int bswz = (bid & 7) * 128 + (bid >> 3);     // XCD k <- image k (1024%8==0)
    const int wid  = bswz * 4 + wv;              // 0..4095

    #pragma unroll 1
    for (int it = 0; it < 2; ++it) {
        int t = wid * 2 + it;                    // 0..8191
        int px0 = t << 4;
        int b = px0 >> 14, hw0 = px0 & 16383;
        int h = hw0 >> 7, x0 = hw0 & 127;
        const unsigned short* xpb = xp + (size_t)b * HWC * CINC;

        f32x4 acc[2];
        acc[0] = (f32x4){0.f,0.f,0.f,0.f};
        acc[1] = (f32x4){0.f,0.f,0.f,0.f};

        #pragma unroll
        for (int kk = 0; kk < 9; ++kk) {
            int y  = h  + kk/3 - 1;
            int xx = x0 + l15 + kk%3 - 1;
            bool val = ((unsigned)y < 128u) && ((unsigned)xx < 128u);
            const uint4* src = (const uint4*)(xpb
                + ((size_t)((y & 127) * 128 + (xx & 127))) * 64 + 8 * l4);
            uint4 z = make_uint4(0u,0u,0u,0u);
            uint4 a0 = val ? src[0] : z;     // ch 8*l4..+7
            uint4 a1 = val ? src[4] : z;     // ch 32+8*l4..+7
            bf16x8 A0 = __builtin_bit_cast(bf16x8, a0);
            bf16x8 A1 = __builtin_bit_cast(bf16x8, a1);
            #pragma unroll
            for (int fn = 0; fn < 2; ++fn) {
                const unsigned short* rw = WcS + (16*fn + l15) * 584 + kk*64 + 8*l4;
                bf16x8 B0 = *(const bf16x8*)(rw);
                bf16x8 B1 = *(const bf16x8*)(rw + 32);
                acc[fn] = __builtin_amdgcn_mfma_f32_16x16x32_bf16(A0, B0, acc[fn], 0,0,0);
                acc[fn] = __builtin_amdgcn_mfma_f32_16x16x32_bf16(A1, B1, acc[fn], 0,0,0);
            }
        }

        #pragma unroll
        for (int fn = 0; fn < 2; ++fn) {
            int o = 16*fn + l15;
            float vals[4];
            #pragma unroll
            for (int r = 0; r < 4; ++r) {
                float v = acc[fn][r];
                if (o < 18) {
                    v += off_b[o];
                    int k = o >> 1;
                    if ((o & 1) == 0) v += (float)(h - 1 + k/3);
                    else              v += (float)(x0 + 4*l4 + r - 1 + (k - (k/3)*3));
                } else if (o < 27) {
                    v = 2.f / (1.f + __expf(-(v + mod_b[o - 18])));
                }
                vals[r] = v;
            }
            if (o < 27)
                *(f32x4*)(coords + (size_t)o * NPX + px0 + 4*l4) =
                    (f32x4){vals[0], vals[1], vals[2], vals[3]};
        }
    }
}

// ---------------- K3: gather + einsum, barrier-free per-wave M=16 N=128 -----
// 128 blocks x 1024 threads (16 waves => 4 waves/SIMD, 1 block/CU).
// XCD-swizzled: XCD k processes image k only => gathers hit per-XCD L2.
// Wb staged once in LDS (149.5 KB). Lane (l15,l4): px = px0+l15, channel
// chunks {8*l4.., 32+8*l4..} == exact MFMA A-frag layout.
__global__ __launch_bounds__(1024, 4) void gather_einsum(
        const unsigned short* __restrict__ xp,
        const unsigned short* __restrict__ Wb,
        const float* __restrict__ coords,
        float* __restrict__ out)
{
    __shared__ uint4 WbL[128 * 73];   // 149504 B, pitch 584 shorts
    int tid = threadIdx.x;
    for (int j = tid; j < 128 * 72; j += 1024) {
        int row = j / 72, c16 = j % 72;
        WbL[row * 73 + c16] = ((const uint4*)Wb)[j];
    }
    __syncthreads();
    const unsigned short* WbS = (const unsigned short*)WbL;

    const int lane = tid & 63;
    const int wv   = tid >> 6;      // 0..15
    const int l15  = lane & 15;
    const int l4   = lane >> 4;
    int bid = (int)blockIdx.x;
    int bswz = (bid & 7) * 16 + (bid >> 3);   // XCD k <- image k (128%8==0)

    #pragma unroll 1
    for (int i = 0; i < 4; ++i) {
        int t = (bswz * 16 + wv) * 4 + i;     // 0..8191
        int px0 = t << 4;
        int b = px0 >> 14, hw0 = px0 & 16383;
        const unsigned short* xpb = xp + (size_t)b * HWC * CINC;
        int pxl = px0 + l15;

        // coords for this lane's px (all 9 kk)
        float pyv[9], pxv[9], mmv[9];
        #pragma unroll
        for (int kk = 0; kk < 9; ++kk) {
            pyv[kk] = coords[(size_t)(2*kk    ) * NPX + pxl];
            pxv[kk] = coords[(size_t)(2*kk + 1) * NPX + pxl];
            mmv[kk] = coords[(size_t)(18 + kk ) * NPX + pxl];
        }

        f32x4 acc[8];
        #pragma unroll
        for (int fn = 0; fn < 8; ++fn) acc[fn] = (f32x4){0.f,0.f,0.f,0.f};

        uint4 cb[2][8];          // [parity][corner*2+chunk]
        float wyA[2], wxA[2], fv[2][4];

        // issue gather loads for kk (parity p)
        #define ISSUE(kk_, p_) do { \
            float Y = pyv[kk_], X = pxv[kk_]; \
            float yf = floorf(Y), xf = floorf(X); \
            wyA[p_] = Y - yf; wxA[p_] = X - xf; \
            int y0 = (int)yf, x0i = (int)xf; \
            int y1 = y0 + 1, x1 = x0i + 1; \
            bool yv0 = (unsigned)y0 < 128u, yv1 = (unsigned)y1 < 128u; \
            bool xv0 = (unsigned)x0i < 128u, xv1 = (unsigned)x1 < 128u; \
            fv[p_][0] = (yv0 && xv0) ? 1.f : 0.f; \
            fv[p_][1] = (yv0 && xv1) ? 1.f : 0.f; \
            fv[p_][2] = (yv1 && xv0) ? 1.f : 0.f; \
            fv[p_][3] = (yv1 && xv1) ? 1.f : 0.f; \
            int yc0 = y0 < 0 ? 0 : (y0 > 127 ? 127 : y0); \
            int yc1 = y1 < 0 ? 0 : (y1 > 127 ? 127 : y1); \
            int xc0 = x0i < 0 ? 0 : (x0i > 127 ? 127 : x0i); \
            int xc1 = x1 < 0 ? 0 : (x1 > 127 ? 127 : x1); \
            const unsigned short* p00 = xpb + (size_t)(yc0*128 + xc0)*64 + 8*l4; \
            const unsigned short* p01 = xpb + (size_t)(yc0*128 + xc1)*64 + 8*l4; \
            const unsigned short* p10 = xpb + (size_t)(yc1*128 + xc0)*64 + 8*l4; \
            const unsigned short* p11 = xpb + (size_t)(yc1*128 + xc1)*64 + 8*l4; \
            cb[p_][0] = *(const uint4*)(p00);      cb[p_][1] = *(const uint4*)(p00 + 32); \
            cb[p_][2] = *(const uint4*)(p01);      cb[p_][3] = *(const uint4*)(p01 + 32); \
            cb[p_][4] = *(const uint4*)(p10);      cb[p_][5] = *(const uint4*)(p10 + 32); \
            cb[p_][6] = *(const uint4*)(p11);      cb[p_][7] = *(const uint4*)(p11 + 32); \
        } while(0)

        ISSUE(0, 0);

        #pragma unroll
        for (int kk = 0; kk < 9; ++kk) {
            const int p = kk & 1;
            if (kk < 8) {
                const int pn = (kk + 1) & 1;
                ISSUE(kk + 1, pn);
            }
            // weights (validity + modulation folded)
            float m = mmv[kk];
            float oy = wyA[p], ox = wxA[p];
            float u00 = (1.f - oy) * (1.f - ox) * m * fv[p][0];
            float u01 = (1.f - oy) * ox         * m * fv[p][1];
            float u10 = oy * (1.f - ox)         * m * fv[p][2];
            float u11 = oy * ox                 * m * fv[p][3];

            unsigned pk0[4], pk1[4];
            #pragma unroll
            for (int d = 0; d < 4; ++d) {
                unsigned q00, q01, q10, q11;
                q00 = cb[p][0][d]; q01 = cb[p][2][d]; q10 = cb[p][4][d]; q11 = cb[p][6][d];
                {
                    float slo = bf_lo(q00)*u00 + bf_lo(q01)*u01 + bf_lo(q10)*u10 + bf_lo(q11)*u11;
                    float shi = bf_hi(q00)*u00 + bf_hi(q01)*u01 + bf_hi(q10)*u10 + bf_hi(q11)*u11;
                    pk0[d] = (unsigned)f2bf(slo) | ((unsigned)f2bf(shi) << 16);
                }
                q00 = cb[p][1][d]; q01 = cb[p][3][d]; q10 = cb[p][5][d]; q11 = cb[p][7][d];
                {
                    float slo = bf_lo(q00)*u00 + bf_lo(q01)*u01 + bf_lo(q10)*u10 + bf_lo(q11)*u11;
                    float shi = bf_hi(q00)*u00 + bf_hi(q01)*u01 + bf_hi(q10)*u10 + bf_hi(q11)*u11;
                    pk1[d] = (unsigned)f2bf(slo) | ((unsigned)f2bf(shi) << 16);
                }
            }
            bf16x8 A0 = __builtin_bit_cast(bf16x8, make_uint4(pk0[0], pk0[1], pk0[2], pk0[3]));
            bf16x8 A1 = __builtin_bit_cast(bf16x8, make_uint4(pk1[0], pk1[1], pk1[2], pk1[3]));

            #pragma unroll
            for (int fn = 0; fn < 8; ++fn) {
                const unsigned short* rw = WbS + (size_t)(16*fn + l15) * 584 + kk*64 + 8*l4;
                bf16x8 B0 = *(const bf16x8*)(rw);
                bf16x8 B1 = *(const bf16x8*)(rw + 32);
                acc[fn] = __builtin_amdgcn_mfma_f32_16x16x32_bf16(A0, B0, acc[fn], 0,0,0);
                acc[fn] = __builtin_amdgcn_mfma_f32_16x16x32_bf16(A1, B1, acc[fn], 0,0,0);
            }
        }
        #undef ISSUE

        float* ob = out + (size_t)b * COUTC * HWC + hw0 + 4*l4;
        #pragma unroll
        for (int fn = 0; fn < 8; ++fn)
            *(f32x4*)(ob + (size_t)(16*fn + l15) * HWC) = acc[fn];
    }
}

extern "C" void kernel_launch(void* const* d_in, const int* in_sizes, int n_in,
                              void* d_out, int out_size, void* d_ws, size_t ws_size,
                              hipStream_t stream)
{
    const float* x     = (const float*)d_in[0];
    const float* pre_w = (const float*)d_in[1];
    const float* pre_b = (const float*)d_in[2];
    const float* off_w = (const float*)d_in[3];
    const float* off_b = (const float*)d_in[4];
    const float* mod_w = (const float*)d_in[5];
    const float* mod_b = (const float*)d_in[6];
    const float* reg_w = (const float*)d_in[7];
    float* out = (float*)d_out;

    unsigned short* xp = (unsigned short*)d_ws;                                 // 16,777,216 B
    unsigned short* Wb = (unsigned short*)((char*)d_ws + 16777216);             //    147,456 B
    unsigned short* Wc = (unsigned short*)((char*)d_ws + 16777216 + 147456);    //     36,864 B
    float* coords = (float*)((char*)d_ws + 16777216 + 147456 + 36864);          // 16,777,216 B

    prep_weights<<<dim3(360),  dim3(256), 0, stream>>>(off_w, mod_w, reg_w, Wb, Wc);
    conv1x1    <<<dim3(512),  dim3(256), 0, stream>>>(x, pre_w, pre_b, xp);
    offset_conv<<<dim3(1024), dim3(256), 0, stream>>>(xp, Wc, off_b, mod_b, coords);
    gather_einsum<<<dim3(128), dim3(1024), 0, stream>>>(xp, Wb, coords, out);
}

// Round 4
// 454.242 us; speedup vs baseline: 1.5160x; 1.5160x over previous
//
#include <hip/hip_runtime.h>
#include <hip/hip_bf16.h>
#include <cstdint>
#include <cstddef>

#define BATCH 8
#define CINC  64
#define HH    128
#define WWW   128
#define COUTC 128
#define KKC   9
#define KDIM  576   // KK*CIN, k = kk*64 + c
#define HWC   (HH*WWW)      // 16384
#define NPX   (BATCH*HWC)   // 131072

typedef float f32x4 __attribute__((ext_vector_type(4)));
typedef short bf16x8 __attribute__((ext_vector_type(8)));

static __device__ __forceinline__ unsigned short f2bf(float f){
    unsigned u = __builtin_bit_cast(unsigned, f);
    u += 0x7fffu + ((u >> 16) & 1u);
    return (unsigned short)(u >> 16);
}
static __device__ __forceinline__ float bf_lo(unsigned u){
    return __builtin_bit_cast(float, u << 16);
}
static __device__ __forceinline__ float bf_hi(unsigned u){
    return __builtin_bit_cast(float, u & 0xffff0000u);
}

// ---------------- K0: pack weights to bf16, k = kk*64+c, row-major [o][k] ----
__global__ __launch_bounds__(256) void prep_weights(
        const float* __restrict__ off_w, const float* __restrict__ mod_w,
        const float* __restrict__ reg_w,
        unsigned short* __restrict__ Wb, unsigned short* __restrict__ Wc)
{
    int idx = blockIdx.x * 256 + threadIdx.x;
    if (idx < COUTC * KDIM) {
        int o = idx / KDIM, k = idx % KDIM;
        int kk = k >> 6, c = k & 63;
        Wb[idx] = f2bf(reg_w[(o * CINC + c) * KKC + kk]);
    }
    int idx2 = idx - COUTC * KDIM;
    if (idx2 >= 0 && idx2 < 32 * KDIM) {
        int o = idx2 / KDIM, k = idx2 % KDIM;
        int kk = k >> 6, c = k & 63;
        float v = 0.f;
        if (o < 18)      v = off_w[(o * CINC + c) * KKC + kk];      // o = kk*2+d
        else if (o < 27) v = mod_w[((o - 18) * CINC + c) * KKC + kk];
        Wc[idx2] = f2bf(v);
    }
}

// ---------------- K1: 1x1 conv, NCHW f32 -> NHWC bf16 ----------------------
// XCD-pinned: image k produced on XCD k (warms its L2 for the consumers).
__global__ __launch_bounds__(256) void conv1x1(
        const float* __restrict__ x, const float* __restrict__ pre_w,
        const float* __restrict__ pre_b, unsigned short* __restrict__ xp)
{
    __shared__ float wlds[CINC * CINC];   // [ci][co]
    __shared__ float blds[CINC];
    int tid = threadIdx.x;
    for (int i = tid; i < CINC * CINC; i += 256) {
        int co = i >> 6, ci = i & 63;
        wlds[ci * 64 + co] = pre_w[i];    // pre_w[co][ci][1][1]
    }
    if (tid < CINC) blds[tid] = pre_b[tid];
    __syncthreads();

    int bid = (int)blockIdx.x;
    int bswz = (bid & 7) * 64 + (bid >> 3);   // 512 blocks: image = bid&7
    int px = bswz * 256 + tid;
    int b = px >> 14, hw = px & 16383;
    float acc[CINC];
    #pragma unroll
    for (int co = 0; co < CINC; ++co) acc[co] = blds[co];
    for (int ci = 0; ci < CINC; ++ci) {
        float xv = x[(size_t)(b * CINC + ci) * HWC + hw];
        #pragma unroll
        for (int co = 0; co < CINC; ++co) acc[co] += xv * wlds[ci * 64 + co];
    }
    unsigned pk[32];
    #pragma unroll
    for (int j = 0; j < 32; ++j)
        pk[j] = (unsigned)f2bf(acc[2*j]) | ((unsigned)f2bf(acc[2*j+1]) << 16);
    uint4* dst = (uint4*)(xp + (size_t)px * 64);
    #pragma unroll
    for (int q = 0; q < 8; ++q)
        dst[q] = make_uint4(pk[4*q], pk[4*q+1], pk[4*q+2], pk[4*q+3]);
}

// ---------------- K2: offset/mask 3x3 conv -> coords[32][NPX] ---------------
// 1024 blocks x 256 threads (4 waves). XCD-pinned: image k on XCD k.
__global__ __launch_bounds__(256) void offset_conv(
        const unsigned short* __restrict__ xp,
        const unsigned short* __restrict__ Wc,
        const float* __restrict__ off_b,
        const float* __restrict__ mod_b,
        float* __restrict__ coords)
{
    __shared__ uint4 WcL[32 * 73];   // pitch 73 uint4 = 584 shorts
    int tid = threadIdx.x;
    for (int j = tid; j < 32 * 72; j += 256) {
        int row = j / 72, c16 = j % 72;
        WcL[row * 73 + c16] = ((const uint4*)Wc)[j];
    }
    __syncthreads();
    const unsigned short* WcS = (const unsigned short*)WcL;

    const int lane = tid & 63;
    const int wv   = tid >> 6;
    const int l15  = lane & 15;
    const int l4   = lane >> 4;
    int bid = (int)blockIdx.x;
    int bswz = (bid & 7) * 128 + (bid >> 3);     // image = bid&7
    const int wid  = bswz * 4 + wv;              // 0..4095

    #pragma unroll 1
    for (int it = 0; it < 2; ++it) {
        int t = wid * 2 + it;                    // 0..8191
        int px0 = t << 4;
        int b = px0 >> 14, hw0 = px0 & 16383;
        int h = hw0 >> 7, x0 = hw0 & 127;
        const unsigned short* xpb = xp + (size_t)b * HWC * CINC;

        f32x4 acc[2];
        acc[0] = (f32x4){0.f,0.f,0.f,0.f};
        acc[1] = (f32x4){0.f,0.f,0.f,0.f};

        #pragma unroll
        for (int kk = 0; kk < 9; ++kk) {
            int y  = h  + kk/3 - 1;
            int xx = x0 + l15 + kk%3 - 1;
            bool val = ((unsigned)y < 128u) && ((unsigned)xx < 128u);
            const uint4* src = (const uint4*)(xpb
                + ((size_t)((y & 127) * 128 + (xx & 127))) * 64 + 8 * l4);
            uint4 z = make_uint4(0u,0u,0u,0u);
            uint4 a0 = val ? src[0] : z;     // ch 8*l4..+7
            uint4 a1 = val ? src[4] : z;     // ch 32+8*l4..+7
            bf16x8 A0 = __builtin_bit_cast(bf16x8, a0);
            bf16x8 A1 = __builtin_bit_cast(bf16x8, a1);
            #pragma unroll
            for (int fn = 0; fn < 2; ++fn) {
                const unsigned short* rw = WcS + (16*fn + l15) * 584 + kk*64 + 8*l4;
                bf16x8 B0 = *(const bf16x8*)(rw);
                bf16x8 B1 = *(const bf16x8*)(rw + 32);
                acc[fn] = __builtin_amdgcn_mfma_f32_16x16x32_bf16(A0, B0, acc[fn], 0,0,0);
                acc[fn] = __builtin_amdgcn_mfma_f32_16x16x32_bf16(A1, B1, acc[fn], 0,0,0);
            }
        }

        #pragma unroll
        for (int fn = 0; fn < 2; ++fn) {
            int o = 16*fn + l15;
            float vals[4];
            #pragma unroll
            for (int r = 0; r < 4; ++r) {
                float v = acc[fn][r];
                if (o < 18) {
                    v += off_b[o];
                    int k = o >> 1;
                    if ((o & 1) == 0) v += (float)(h - 1 + k/3);
                    else              v += (float)(x0 + 4*l4 + r - 1 + (k - (k/3)*3));
                } else if (o < 27) {
                    v = 2.f / (1.f + __expf(-(v + mod_b[o - 18])));
                }
                vals[r] = v;
            }
            if (o < 27)
                *(f32x4*)(coords + (size_t)o * NPX + px0 + 4*l4) =
                    (f32x4){vals[0], vals[1], vals[2], vals[3]};
        }
    }
}

// ---------------- K3: gather + einsum, barrier-free per-wave M=16 N=128 -----
// 256 blocks x 512 threads (8 waves, 2/SIMD, 1 block/CU). XCD-pinned:
// XCD k gathers only from image k -> 2 MB xp slice stays L2-resident.
// Wb staged once in LDS (149.5 KB). Lane (l15,l4): px = px0+l15, channel
// chunks {8*l4.., 32+8*l4..} == exact MFMA A-frag layout.
__global__ __launch_bounds__(512, 2) void gather_einsum(
        const unsigned short* __restrict__ xp,
        const unsigned short* __restrict__ Wb,
        const float* __restrict__ coords,
        float* __restrict__ out)
{
    __shared__ uint4 WbL[128 * 73];   // 149504 B, pitch 584 shorts
    int tid = threadIdx.x;
    for (int j = tid; j < 128 * 72; j += 512) {
        int row = j / 72, c16 = j % 72;
        WbL[row * 73 + c16] = ((const uint4*)Wb)[j];
    }
    __syncthreads();
    const unsigned short* WbS = (const unsigned short*)WbL;

    const int lane = tid & 63;
    const int wv   = tid >> 6;
    const int l15  = lane & 15;
    const int l4   = lane >> 4;
    int bid = (int)blockIdx.x;
    int bswz = (bid & 7) * 32 + (bid >> 3);   // 256 blocks: image = bid&7

    #pragma unroll 1
    for (int i = 0; i < 4; ++i) {
        int t = bswz * 32 + wv * 4 + i;
        int px0 = t << 4;
        int b = px0 >> 14, hw0 = px0 & 16383;
        const unsigned short* xpb = xp + (size_t)b * HWC * CINC;
        int pxl = px0 + l15;

        // coords for this lane's px (all 9 kk)
        float pyv[9], pxv[9], mmv[9];
        #pragma unroll
        for (int kk = 0; kk < 9; ++kk) {
            pyv[kk] = coords[(size_t)(2*kk    ) * NPX + pxl];
            pxv[kk] = coords[(size_t)(2*kk + 1) * NPX + pxl];
            mmv[kk] = coords[(size_t)(18 + kk ) * NPX + pxl];
        }

        f32x4 acc[8];
        #pragma unroll
        for (int fn = 0; fn < 8; ++fn) acc[fn] = (f32x4){0.f,0.f,0.f,0.f};

        uint4 cb[2][8];          // [parity][corner*2+chunk]
        float wyA[2], wxA[2], fv[2][4];

        // issue gather loads for kk (parity p)
        #define ISSUE(kk_, p_) do { \
            float Y = pyv[kk_], X = pxv[kk_]; \
            float yf = floorf(Y), xf = floorf(X); \
            wyA[p_] = Y - yf; wxA[p_] = X - xf; \
            int y0 = (int)yf, x0i = (int)xf; \
            int y1 = y0 + 1, x1 = x0i + 1; \
            bool yv0 = (unsigned)y0 < 128u, yv1 = (unsigned)y1 < 128u; \
            bool xv0 = (unsigned)x0i < 128u, xv1 = (unsigned)x1 < 128u; \
            fv[p_][0] = (yv0 && xv0) ? 1.f : 0.f; \
            fv[p_][1] = (yv0 && xv1) ? 1.f : 0.f; \
            fv[p_][2] = (yv1 && xv0) ? 1.f : 0.f; \
            fv[p_][3] = (yv1 && xv1) ? 1.f : 0.f; \
            int yc0 = y0 < 0 ? 0 : (y0 > 127 ? 127 : y0); \
            int yc1 = y1 < 0 ? 0 : (y1 > 127 ? 127 : y1); \
            int xc0 = x0i < 0 ? 0 : (x0i > 127 ? 127 : x0i); \
            int xc1 = x1 < 0 ? 0 : (x1 > 127 ? 127 : x1); \
            const unsigned short* p00 = xpb + (size_t)(yc0*128 + xc0)*64 + 8*l4; \
            const unsigned short* p01 = xpb + (size_t)(yc0*128 + xc1)*64 + 8*l4; \
            const unsigned short* p10 = xpb + (size_t)(yc1*128 + xc0)*64 + 8*l4; \
            const unsigned short* p11 = xpb + (size_t)(yc1*128 + xc1)*64 + 8*l4; \
            cb[p_][0] = *(const uint4*)(p00);      cb[p_][1] = *(const uint4*)(p00 + 32); \
            cb[p_][2] = *(const uint4*)(p01);      cb[p_][3] = *(const uint4*)(p01 + 32); \
            cb[p_][4] = *(const uint4*)(p10);      cb[p_][5] = *(const uint4*)(p10 + 32); \
            cb[p_][6] = *(const uint4*)(p11);      cb[p_][7] = *(const uint4*)(p11 + 32); \
        } while(0)

        ISSUE(0, 0);

        #pragma unroll
        for (int kk = 0; kk < 9; ++kk) {
            const int p = kk & 1;
            if (kk < 8) {
                const int pn = (kk + 1) & 1;
                ISSUE(kk + 1, pn);
            }
            // weights (validity + modulation folded)
            float m = mmv[kk];
            float oy = wyA[p], ox = wxA[p];
            float u00 = (1.f - oy) * (1.f - ox) * m * fv[p][0];
            float u01 = (1.f - oy) * ox         * m * fv[p][1];
            float u10 = oy * (1.f - ox)         * m * fv[p][2];
            float u11 = oy * ox                 * m * fv[p][3];

            unsigned pk0[4], pk1[4];
            #pragma unroll
            for (int d = 0; d < 4; ++d) {
                unsigned q00, q01, q10, q11;
                q00 = cb[p][0][d]; q01 = cb[p][2][d]; q10 = cb[p][4][d]; q11 = cb[p][6][d];
                {
                    float slo = bf_lo(q00)*u00 + bf_lo(q01)*u01 + bf_lo(q10)*u10 + bf_lo(q11)*u11;
                    float shi = bf_hi(q00)*u00 + bf_hi(q01)*u01 + bf_hi(q10)*u10 + bf_hi(q11)*u11;
                    pk0[d] = (unsigned)f2bf(slo) | ((unsigned)f2bf(shi) << 16);
                }
                q00 = cb[p][1][d]; q01 = cb[p][3][d]; q10 = cb[p][5][d]; q11 = cb[p][7][d];
                {
                    float slo = bf_lo(q00)*u00 + bf_lo(q01)*u01 + bf_lo(q10)*u10 + bf_lo(q11)*u11;
                    float shi = bf_hi(q00)*u00 + bf_hi(q01)*u01 + bf_hi(q10)*u10 + bf_hi(q11)*u11;
                    pk1[d] = (unsigned)f2bf(slo) | ((unsigned)f2bf(shi) << 16);
                }
            }
            bf16x8 A0 = __builtin_bit_cast(bf16x8, make_uint4(pk0[0], pk0[1], pk0[2], pk0[3]));
            bf16x8 A1 = __builtin_bit_cast(bf16x8, make_uint4(pk1[0], pk1[1], pk1[2], pk1[3]));

            #pragma unroll
            for (int fn = 0; fn < 8; ++fn) {
                const unsigned short* rw = WbS + (size_t)(16*fn + l15) * 584 + kk*64 + 8*l4;
                bf16x8 B0 = *(const bf16x8*)(rw);
                bf16x8 B1 = *(const bf16x8*)(rw + 32);
                acc[fn] = __builtin_amdgcn_mfma_f32_16x16x32_bf16(A0, B0, acc[fn], 0,0,0);
                acc[fn] = __builtin_amdgcn_mfma_f32_16x16x32_bf16(A1, B1, acc[fn], 0,0,0);
            }
        }
        #undef ISSUE

        float* ob = out + (size_t)b * COUTC * HWC + hw0 + 4*l4;
        #pragma unroll
        for (int fn = 0; fn < 8; ++fn)
            *(f32x4*)(ob + (size_t)(16*fn + l15) * HWC) = acc[fn];
    }
}

extern "C" void kernel_launch(void* const* d_in, const int* in_sizes, int n_in,
                              void* d_out, int out_size, void* d_ws, size_t ws_size,
                              hipStream_t stream)
{
    const float* x     = (const float*)d_in[0];
    const float* pre_w = (const float*)d_in[1];
    const float* pre_b = (const float*)d_in[2];
    const float* off_w = (const float*)d_in[3];
    const float* off_b = (const float*)d_in[4];
    const float* mod_w = (const float*)d_in[5];
    const float* mod_b = (const float*)d_in[6];
    const float* reg_w = (const float*)d_in[7];
    float* out = (float*)d_out;

    unsigned short* xp = (unsigned short*)d_ws;                                 // 16,777,216 B
    unsigned short* Wb = (unsigned short*)((char*)d_ws + 16777216);             //    147,456 B
    unsigned short* Wc = (unsigned short*)((char*)d_ws + 16777216 + 147456);    //     36,864 B
    float* coords = (float*)((char*)d_ws + 16777216 + 147456 + 36864);          // 16,777,216 B

    prep_weights<<<dim3(360),  dim3(256), 0, stream>>>(off_w, mod_w, reg_w, Wb, Wc);
    conv1x1    <<<dim3(512),  dim3(256), 0, stream>>>(x, pre_w, pre_b, xp);
    offset_conv<<<dim3(1024), dim3(256), 0, stream>>>(xp, Wc, off_b, mod_b, coords);
    gather_einsum<<<dim3(256), dim3(512), 0, stream>>>(xp, Wb, coords, out);
}

// Round 5
// 220.411 us; speedup vs baseline: 3.1243x; 2.0609x over previous
//
#include <hip/hip_runtime.h>
#include <hip/hip_bf16.h>
#include <cstdint>
#include <cstddef>

#define BATCH 8
#define CINC  64
#define HH    128
#define WWW   128
#define COUTC 128
#define KKC   9
#define KDIM  576   // KK*CIN, k = kk*64 + c
#define HWC   (HH*WWW)      // 16384
#define NPX   (BATCH*HWC)   // 131072

typedef float f32x4 __attribute__((ext_vector_type(4)));
typedef short bf16x8 __attribute__((ext_vector_type(8)));

static __device__ __forceinline__ unsigned short f2bf(float f){
    unsigned u = __builtin_bit_cast(unsigned, f);
    u += 0x7fffu + ((u >> 16) & 1u);
    return (unsigned short)(u >> 16);
}
static __device__ __forceinline__ float bf_lo(unsigned u){
    return __builtin_bit_cast(float, u << 16);
}
static __device__ __forceinline__ float bf_hi(unsigned u){
    return __builtin_bit_cast(float, u & 0xffff0000u);
}

// ---------------- K0: pack weights to bf16, k = kk*64+c, row-major [o][k] ----
__global__ __launch_bounds__(256) void prep_weights(
        const float* __restrict__ off_w, const float* __restrict__ mod_w,
        const float* __restrict__ reg_w,
        unsigned short* __restrict__ Wb, unsigned short* __restrict__ Wc)
{
    int idx = blockIdx.x * 256 + threadIdx.x;
    if (idx < COUTC * KDIM) {
        int o = idx / KDIM, k = idx % KDIM;
        int kk = k >> 6, c = k & 63;
        Wb[idx] = f2bf(reg_w[(o * CINC + c) * KKC + kk]);
    }
    int idx2 = idx - COUTC * KDIM;
    if (idx2 >= 0 && idx2 < 32 * KDIM) {
        int o = idx2 / KDIM, k = idx2 % KDIM;
        int kk = k >> 6, c = k & 63;
        float v = 0.f;
        if (o < 18)      v = off_w[(o * CINC + c) * KKC + kk];      // o = kk*2+d
        else if (o < 27) v = mod_w[((o - 18) * CINC + c) * KKC + kk];
        Wc[idx2] = f2bf(v);
    }
}

// ---------------- K1: 1x1 conv, NCHW f32 -> NHWC bf16 ----------------------
__global__ __launch_bounds__(256) void conv1x1(
        const float* __restrict__ x, const float* __restrict__ pre_w,
        const float* __restrict__ pre_b, unsigned short* __restrict__ xp)
{
    __shared__ float wlds[CINC * CINC];   // [ci][co]
    __shared__ float blds[CINC];
    int tid = threadIdx.x;
    for (int i = tid; i < CINC * CINC; i += 256) {
        int co = i >> 6, ci = i & 63;
        wlds[ci * 64 + co] = pre_w[i];    // pre_w[co][ci][1][1]
    }
    if (tid < CINC) blds[tid] = pre_b[tid];
    __syncthreads();

    int bid = (int)blockIdx.x;
    int bswz = (bid & 7) * 64 + (bid >> 3);   // 512 blocks: image = bid&7
    int px = bswz * 256 + tid;
    int b = px >> 14, hw = px & 16383;
    float acc[CINC];
    #pragma unroll
    for (int co = 0; co < CINC; ++co) acc[co] = blds[co];
    for (int ci = 0; ci < CINC; ++ci) {
        float xv = x[(size_t)(b * CINC + ci) * HWC + hw];
        #pragma unroll
        for (int co = 0; co < CINC; ++co) acc[co] += xv * wlds[ci * 64 + co];
    }
    unsigned pk[32];
    #pragma unroll
    for (int j = 0; j < 32; ++j)
        pk[j] = (unsigned)f2bf(acc[2*j]) | ((unsigned)f2bf(acc[2*j+1]) << 16);
    uint4* dst = (uint4*)(xp + (size_t)px * 64);
    #pragma unroll
    for (int q = 0; q < 8; ++q)
        dst[q] = make_uint4(pk[4*q], pk[4*q+1], pk[4*q+2], pk[4*q+3]);
}

// ---------------- K2: offset/mask 3x3 conv -> coords[32][NPX] ---------------
__global__ __launch_bounds__(256) void offset_conv(
        const unsigned short* __restrict__ xp,
        const unsigned short* __restrict__ Wc,
        const float* __restrict__ off_b,
        const float* __restrict__ mod_b,
        float* __restrict__ coords)
{
    __shared__ uint4 WcL[32 * 73];   // pitch 73 uint4 = 584 shorts
    int tid = threadIdx.x;
    for (int j = tid; j < 32 * 72; j += 256) {
        int row = j / 72, c16 = j % 72;
        WcL[row * 73 + c16] = ((const uint4*)Wc)[j];
    }
    __syncthreads();
    const unsigned short* WcS = (const unsigned short*)WcL;

    const int lane = tid & 63;
    const int wv   = tid >> 6;
    const int l15  = lane & 15;
    const int l4   = lane >> 4;
    int bid = (int)blockIdx.x;
    int bswz = (bid & 7) * 128 + (bid >> 3);     // image = bid&7
    const int wid  = bswz * 4 + wv;              // 0..4095

    #pragma unroll 1
    for (int it = 0; it < 2; ++it) {
        int t = wid * 2 + it;                    // 0..8191
        int px0 = t << 4;
        int b = px0 >> 14, hw0 = px0 & 16383;
        int h = hw0 >> 7, x0 = hw0 & 127;
        const unsigned short* xpb = xp + (size_t)b * HWC * CINC;

        f32x4 acc[2];
        acc[0] = (f32x4){0.f,0.f,0.f,0.f};
        acc[1] = (f32x4){0.f,0.f,0.f,0.f};

        #pragma unroll
        for (int kk = 0; kk < 9; ++kk) {
            int y  = h  + kk/3 - 1;
            int xx = x0 + l15 + kk%3 - 1;
            bool val = ((unsigned)y < 128u) && ((unsigned)xx < 128u);
            const uint4* src = (const uint4*)(xpb
                + ((size_t)((y & 127) * 128 + (xx & 127))) * 64 + 8 * l4);
            uint4 z = make_uint4(0u,0u,0u,0u);
            uint4 a0 = val ? src[0] : z;     // ch 8*l4..+7
            uint4 a1 = val ? src[4] : z;     // ch 32+8*l4..+7
            bf16x8 A0 = __builtin_bit_cast(bf16x8, a0);
            bf16x8 A1 = __builtin_bit_cast(bf16x8, a1);
            #pragma unroll
            for (int fn = 0; fn < 2; ++fn) {
                const unsigned short* rw = WcS + (16*fn + l15) * 584 + kk*64 + 8*l4;
                bf16x8 B0 = *(const bf16x8*)(rw);
                bf16x8 B1 = *(const bf16x8*)(rw + 32);
                acc[fn] = __builtin_amdgcn_mfma_f32_16x16x32_bf16(A0, B0, acc[fn], 0,0,0);
                acc[fn] = __builtin_amdgcn_mfma_f32_16x16x32_bf16(A1, B1, acc[fn], 0,0,0);
            }
        }

        #pragma unroll
        for (int fn = 0; fn < 2; ++fn) {
            int o = 16*fn + l15;
            float vals[4];
            #pragma unroll
            for (int r = 0; r < 4; ++r) {
                float v = acc[fn][r];
                if (o < 18) {
                    v += off_b[o];
                    int k = o >> 1;
                    if ((o & 1) == 0) v += (float)(h - 1 + k/3);
                    else              v += (float)(x0 + 4*l4 + r - 1 + (k - (k/3)*3));
                } else if (o < 27) {
                    v = 2.f / (1.f + __expf(-(v + mod_b[o - 18])));
                }
                vals[r] = v;
            }
            if (o < 27)
                *(f32x4*)(coords + (size_t)o * NPX + px0 + 4*l4) =
                    (f32x4){vals[0], vals[1], vals[2], vals[3]};
        }
    }
}

// ---------------- K3: gather + einsum with LDS-staged sample window ---------
// 512 blocks x 512 threads (8 waves). Block = 2 output rows (256 px) of one
// image. Stage xp rows h0-3..h0+4 (8 rows, pitch 144B) into LDS once; all
// bilinear corner reads are ds_read_b128 (~120cy). Out-of-window samples
// (P~1e-5, offsets sigma=0.24) take a predicated global fallback.
// Wave = 32 px (2 subtiles of M=16), N=128 couts; B-frags from global (L2-hot).
// Epilogue: acc -> LDS [cout][256px] -> 1KB full-line stores.
__global__ __launch_bounds__(512, 2) void gather_einsum(
        const unsigned short* __restrict__ xp,
        const unsigned short* __restrict__ Wb,
        const float* __restrict__ coords,
        float* __restrict__ out)
{
    __shared__ char smem[147456];                 // window 8*128*144B; reused as epi
    unsigned short* win = (unsigned short*)smem;  // [(wr*128+x)*72 + s*32 + l4*8]
    float* epi = (float*)smem;                    // [128 cout][260 f32 pitch]

    const int tid  = (int)threadIdx.x;
    const int lane = tid & 63;
    const int wv   = tid >> 6;       // 0..7
    const int l15  = lane & 15;
    const int l4   = lane >> 4;

    int bid = (int)blockIdx.x;
    int bswz = (bid & 7) * 64 + (bid >> 3);   // image = bid&7 (512%8==0)
    const int b  = bswz >> 6;
    const int h0 = (bswz & 63) * 2;           // first of 2 output rows

    const unsigned short* xpb = xp + (size_t)b * HWC * CINC;

    // ---- stage window: rows h0-3 .. h0+4 ----
    #pragma unroll
    for (int i = 0; i < 16; ++i) {
        int c = i * 512 + tid;            // 0..8191 16B-chunks
        int r = c >> 10;                  // window row 0..7
        int c10 = c & 1023;
        int xph = c10 >> 3, g = c10 & 7;  // px in row, chunk
        int y = h0 - 3 + r;
        uint4 v = make_uint4(0u,0u,0u,0u);
        if ((unsigned)y < 128u)
            v = *(const uint4*)(xpb + ((size_t)y * 128 + xph) * 64 + g * 8);
        *(uint4*)((char*)win + ((r * 128 + xph) * 144 + g * 16)) = v;
    }
    __syncthreads();

    // ---- per-wave coords: 2 subtiles x 9 kk ----
    const int cbase = b * HWC + h0 * 128 + wv * 32;   // block px base + wave offset
    float cy[2][9], cx[2][9], cm[2][9];
    #pragma unroll
    for (int j = 0; j < 2; ++j) {
        int pxl = cbase + j * 16 + l15;
        #pragma unroll
        for (int kk = 0; kk < 9; ++kk) {
            cy[j][kk] = coords[(size_t)(2*kk    ) * NPX + pxl];
            cx[j][kk] = coords[(size_t)(2*kk + 1) * NPX + pxl];
            cm[j][kk] = coords[(size_t)(18 + kk ) * NPX + pxl];
        }
    }

    f32x4 acc[2][8];
    #pragma unroll
    for (int j = 0; j < 2; ++j)
        #pragma unroll
        for (int fn = 0; fn < 8; ++fn) acc[j][fn] = (f32x4){0.f,0.f,0.f,0.f};

    #pragma unroll
    for (int kk = 0; kk < 9; ++kk) {
        #pragma unroll
        for (int j = 0; j < 2; ++j) {
            float Y = cy[j][kk], X = cx[j][kk], m = cm[j][kk];
            float yf = floorf(Y), xf = floorf(X);
            float wy = Y - yf, wx = X - xf;
            int y0 = (int)yf, x0i = (int)xf;
            int y1 = y0 + 1, x1 = x0i + 1;
            bool yv0 = (unsigned)y0 < 128u, yv1 = (unsigned)y1 < 128u;
            bool xv0 = (unsigned)x0i < 128u, xv1 = (unsigned)x1 < 128u;
            int xc0 = x0i < 0 ? 0 : (x0i > 127 ? 127 : x0i);
            int xc1 = x1  < 0 ? 0 : (x1  > 127 ? 127 : x1);
            int wr0 = y0 - (h0 - 3), wr1 = wr0 + 1;
            int wc0 = wr0 < 0 ? 0 : (wr0 > 7 ? 7 : wr0);
            int wc1 = wr1 < 0 ? 0 : (wr1 > 7 ? 7 : wr1);

            const char* r00 = (const char*)win + ((wc0*128 + xc0)*144 + l4*16);
            const char* r01 = (const char*)win + ((wc0*128 + xc1)*144 + l4*16);
            const char* r10 = (const char*)win + ((wc1*128 + xc0)*144 + l4*16);
            const char* r11 = (const char*)win + ((wc1*128 + xc1)*144 + l4*16);
            uint4 cb0 = *(const uint4*)(r00);      uint4 cb1 = *(const uint4*)(r00 + 64);
            uint4 cb2 = *(const uint4*)(r01);      uint4 cb3 = *(const uint4*)(r01 + 64);
            uint4 cb4 = *(const uint4*)(r10);      uint4 cb5 = *(const uint4*)(r10 + 64);
            uint4 cb6 = *(const uint4*)(r11);      uint4 cb7 = *(const uint4*)(r11 + 64);

            // rare fallback: sample is inside the image but outside the window
            bool oob = (yv0 && (unsigned)wr0 > 7u) || (yv1 && (unsigned)wr1 > 7u);
            if (__builtin_expect(oob, 0)) {
                int yc0 = y0 < 0 ? 0 : (y0 > 127 ? 127 : y0);
                int yc1 = y1 < 0 ? 0 : (y1 > 127 ? 127 : y1);
                const unsigned short* p00 = xpb + (size_t)(yc0*128 + xc0)*64 + 8*l4;
                const unsigned short* p01 = xpb + (size_t)(yc0*128 + xc1)*64 + 8*l4;
                const unsigned short* p10 = xpb + (size_t)(yc1*128 + xc0)*64 + 8*l4;
                const unsigned short* p11 = xpb + (size_t)(yc1*128 + xc1)*64 + 8*l4;
                cb0 = *(const uint4*)(p00);  cb1 = *(const uint4*)(p00 + 32);
                cb2 = *(const uint4*)(p01);  cb3 = *(const uint4*)(p01 + 32);
                cb4 = *(const uint4*)(p10);  cb5 = *(const uint4*)(p10 + 32);
                cb6 = *(const uint4*)(p11);  cb7 = *(const uint4*)(p11 + 32);
            }

            float u00 = (1.f - wy) * (1.f - wx) * m * ((yv0 && xv0) ? 1.f : 0.f);
            float u01 = (1.f - wy) * wx         * m * ((yv0 && xv1) ? 1.f : 0.f);
            float u10 = wy * (1.f - wx)         * m * ((yv1 && xv0) ? 1.f : 0.f);
            float u11 = wy * wx                 * m * ((yv1 && xv1) ? 1.f : 0.f);

            unsigned pk0[4], pk1[4];
            #pragma unroll
            for (int d = 0; d < 4; ++d) {
                unsigned q00, q01, q10, q11;
                q00 = cb0[d]; q01 = cb2[d]; q10 = cb4[d]; q11 = cb6[d];
                {
                    float slo = bf_lo(q00)*u00 + bf_lo(q01)*u01 + bf_lo(q10)*u10 + bf_lo(q11)*u11;
                    float shi = bf_hi(q00)*u00 + bf_hi(q01)*u01 + bf_hi(q10)*u10 + bf_hi(q11)*u11;
                    pk0[d] = (unsigned)f2bf(slo) | ((unsigned)f2bf(shi) << 16);
                }
                q00 = cb1[d]; q01 = cb3[d]; q10 = cb5[d]; q11 = cb7[d];
                {
                    float slo = bf_lo(q00)*u00 + bf_lo(q01)*u01 + bf_lo(q10)*u10 + bf_lo(q11)*u11;
                    float shi = bf_hi(q00)*u00 + bf_hi(q01)*u01 + bf_hi(q10)*u10 + bf_hi(q11)*u11;
                    pk1[d] = (unsigned)f2bf(slo) | ((unsigned)f2bf(shi) << 16);
                }
            }
            bf16x8 A0 = __builtin_bit_cast(bf16x8, make_uint4(pk0[0], pk0[1], pk0[2], pk0[3]));
            bf16x8 A1 = __builtin_bit_cast(bf16x8, make_uint4(pk1[0], pk1[1], pk1[2], pk1[3]));

            #pragma unroll
            for (int fn = 0; fn < 8; ++fn) {
                const unsigned short* rw = Wb + (size_t)(16*fn + l15) * KDIM + kk*64 + 8*l4;
                bf16x8 B0 = *(const bf16x8*)(rw);
                bf16x8 B1 = *(const bf16x8*)(rw + 32);
                acc[j][fn] = __builtin_amdgcn_mfma_f32_16x16x32_bf16(A0, B0, acc[j][fn], 0,0,0);
                acc[j][fn] = __builtin_amdgcn_mfma_f32_16x16x32_bf16(A1, B1, acc[j][fn], 0,0,0);
            }
        }
    }

    // ---- epilogue: acc -> LDS [cout][px] (pitch 260 f32) -> full-line stores
    __syncthreads();   // done reading window; safe to overwrite
    #pragma unroll
    for (int j = 0; j < 2; ++j)
        #pragma unroll
        for (int fn = 0; fn < 8; ++fn)
            *(f32x4*)(epi + (size_t)(16*fn + l15) * 260 + wv*32 + j*16 + 4*l4) = acc[j][fn];
    __syncthreads();

    float* ob = out + (size_t)b * COUTC * HWC + h0 * 128 + (tid & 63) * 4;
    #pragma unroll
    for (int it = 0; it < 16; ++it) {
        int o = it * 8 + (tid >> 6);
        f32x4 v = *(const f32x4*)(epi + (size_t)o * 260 + (tid & 63) * 4);
        *(f32x4*)(ob + (size_t)o * HWC) = v;
    }
}

extern "C" void kernel_launch(void* const* d_in, const int* in_sizes, int n_in,
                              void* d_out, int out_size, void* d_ws, size_t ws_size,
                              hipStream_t stream)
{
    const float* x     = (const float*)d_in[0];
    const float* pre_w = (const float*)d_in[1];
    const float* pre_b = (const float*)d_in[2];
    const float* off_w = (const float*)d_in[3];
    const float* off_b = (const float*)d_in[4];
    const float* mod_w = (const float*)d_in[5];
    const float* mod_b = (const float*)d_in[6];
    const float* reg_w = (const float*)d_in[7];
    float* out = (float*)d_out;

    unsigned short* xp = (unsigned short*)d_ws;                                 // 16,777,216 B
    unsigned short* Wb = (unsigned short*)((char*)d_ws + 16777216);             //    147,456 B
    unsigned short* Wc = (unsigned short*)((char*)d_ws + 16777216 + 147456);    //     36,864 B
    float* coords = (float*)((char*)d_ws + 16777216 + 147456 + 36864);          // 16,777,216 B

    prep_weights<<<dim3(360),  dim3(256), 0, stream>>>(off_w, mod_w, reg_w, Wb, Wc);
    conv1x1    <<<dim3(512),  dim3(256), 0, stream>>>(x, pre_w, pre_b, xp);
    offset_conv<<<dim3(1024), dim3(256), 0, stream>>>(xp, Wc, off_b, mod_b, coords);
    gather_einsum<<<dim3(512), dim3(512), 0, stream>>>(xp, Wb, coords, out);
}

// Round 6
// 138.985 us; speedup vs baseline: 4.9547x; 1.5859x over previous
//
#include <hip/hip_runtime.h>
#include <hip/hip_bf16.h>
#include <cstdint>
#include <cstddef>

#define BATCH 8
#define CINC  64
#define HH    128
#define WWW   128
#define COUTC 128
#define KKC   9
#define KDIM  576   // KK*CIN, k = kk*64 + c
#define HWC   (HH*WWW)      // 16384
#define NPX   (BATCH*HWC)   // 131072

typedef float f32x4 __attribute__((ext_vector_type(4)));
typedef short bf16x8 __attribute__((ext_vector_type(8)));

static __device__ __forceinline__ unsigned short f2bf(float f){
    unsigned u = __builtin_bit_cast(unsigned, f);
    u += 0x7fffu + ((u >> 16) & 1u);
    return (unsigned short)(u >> 16);
}
static __device__ __forceinline__ float bf_lo(unsigned u){
    return __builtin_bit_cast(float, u << 16);
}
static __device__ __forceinline__ float bf_hi(unsigned u){
    return __builtin_bit_cast(float, u & 0xffff0000u);
}
static __device__ __forceinline__ unsigned cvtpk(float lo, float hi){
    unsigned r;
    asm("v_cvt_pk_bf16_f32 %0, %1, %2" : "=v"(r) : "v"(lo), "v"(hi));
    return r;
}

// ---------------- K0: pack weights to bf16, k = kk*64+c, row-major [o][k] ----
__global__ __launch_bounds__(256) void prep_weights(
        const float* __restrict__ off_w, const float* __restrict__ mod_w,
        const float* __restrict__ reg_w,
        unsigned short* __restrict__ Wb, unsigned short* __restrict__ Wc)
{
    int idx = blockIdx.x * 256 + threadIdx.x;
    if (idx < COUTC * KDIM) {
        int o = idx / KDIM, k = idx % KDIM;
        int kk = k >> 6, c = k & 63;
        Wb[idx] = f2bf(reg_w[(o * CINC + c) * KKC + kk]);
    }
    int idx2 = idx - COUTC * KDIM;
    if (idx2 >= 0 && idx2 < 32 * KDIM) {
        int o = idx2 / KDIM, k = idx2 % KDIM;
        int kk = k >> 6, c = k & 63;
        float v = 0.f;
        if (o < 18)      v = off_w[(o * CINC + c) * KKC + kk];      // o = kk*2+d
        else if (o < 27) v = mod_w[((o - 18) * CINC + c) * KKC + kk];
        Wc[idx2] = f2bf(v);
    }
}

// ---------------- K1: 1x1 conv, NCHW f32 -> NHWC bf16 ----------------------
__global__ __launch_bounds__(256) void conv1x1(
        const float* __restrict__ x, const float* __restrict__ pre_w,
        const float* __restrict__ pre_b, unsigned short* __restrict__ xp)
{
    __shared__ float wlds[CINC * CINC];   // [ci][co]
    __shared__ float blds[CINC];
    int tid = threadIdx.x;
    for (int i = tid; i < CINC * CINC; i += 256) {
        int co = i >> 6, ci = i & 63;
        wlds[ci * 64 + co] = pre_w[i];    // pre_w[co][ci][1][1]
    }
    if (tid < CINC) blds[tid] = pre_b[tid];
    __syncthreads();

    int bid = (int)blockIdx.x;
    int bswz = (bid & 7) * 64 + (bid >> 3);   // 512 blocks: image = bid&7
    int px = bswz * 256 + tid;
    int b = px >> 14, hw = px & 16383;
    float acc[CINC];
    #pragma unroll
    for (int co = 0; co < CINC; ++co) acc[co] = blds[co];
    for (int ci = 0; ci < CINC; ++ci) {
        float xv = x[(size_t)(b * CINC + ci) * HWC + hw];
        #pragma unroll
        for (int co = 0; co < CINC; ++co) acc[co] += xv * wlds[ci * 64 + co];
    }
    unsigned pk[32];
    #pragma unroll
    for (int j = 0; j < 32; ++j)
        pk[j] = (unsigned)f2bf(acc[2*j]) | ((unsigned)f2bf(acc[2*j+1]) << 16);
    uint4* dst = (uint4*)(xp + (size_t)px * 64);
    #pragma unroll
    for (int q = 0; q < 8; ++q)
        dst[q] = make_uint4(pk[4*q], pk[4*q+1], pk[4*q+2], pk[4*q+3]);
}

// ---------------- K2: offset/mask 3x3 conv -> coords[32][NPX] ---------------
__global__ __launch_bounds__(256) void offset_conv(
        const unsigned short* __restrict__ xp,
        const unsigned short* __restrict__ Wc,
        const float* __restrict__ off_b,
        const float* __restrict__ mod_b,
        float* __restrict__ coords)
{
    __shared__ uint4 WcL[32 * 73];   // pitch 73 uint4 = 584 shorts
    int tid = threadIdx.x;
    for (int j = tid; j < 32 * 72; j += 256) {
        int row = j / 72, c16 = j % 72;
        WcL[row * 73 + c16] = ((const uint4*)Wc)[j];
    }
    __syncthreads();
    const unsigned short* WcS = (const unsigned short*)WcL;

    const int lane = tid & 63;
    const int wv   = tid >> 6;
    const int l15  = lane & 15;
    const int l4   = lane >> 4;
    int bid = (int)blockIdx.x;
    int bswz = (bid & 7) * 128 + (bid >> 3);     // image = bid&7
    const int wid  = bswz * 4 + wv;              // 0..4095

    #pragma unroll 1
    for (int it = 0; it < 2; ++it) {
        int t = wid * 2 + it;                    // 0..8191
        int px0 = t << 4;
        int b = px0 >> 14, hw0 = px0 & 16383;
        int h = hw0 >> 7, x0 = hw0 & 127;
        const unsigned short* xpb = xp + (size_t)b * HWC * CINC;

        f32x4 acc[2];
        acc[0] = (f32x4){0.f,0.f,0.f,0.f};
        acc[1] = (f32x4){0.f,0.f,0.f,0.f};

        #pragma unroll
        for (int kk = 0; kk < 9; ++kk) {
            int y  = h  + kk/3 - 1;
            int xx = x0 + l15 + kk%3 - 1;
            bool val = ((unsigned)y < 128u) && ((unsigned)xx < 128u);
            const uint4* src = (const uint4*)(xpb
                + ((size_t)((y & 127) * 128 + (xx & 127))) * 64 + 8 * l4);
            uint4 z = make_uint4(0u,0u,0u,0u);
            uint4 a0 = val ? src[0] : z;     // ch 8*l4..+7
            uint4 a1 = val ? src[4] : z;     // ch 32+8*l4..+7
            bf16x8 A0 = __builtin_bit_cast(bf16x8, a0);
            bf16x8 A1 = __builtin_bit_cast(bf16x8, a1);
            #pragma unroll
            for (int fn = 0; fn < 2; ++fn) {
                const unsigned short* rw = WcS + (16*fn + l15) * 584 + kk*64 + 8*l4;
                bf16x8 B0 = *(const bf16x8*)(rw);
                bf16x8 B1 = *(const bf16x8*)(rw + 32);
                acc[fn] = __builtin_amdgcn_mfma_f32_16x16x32_bf16(A0, B0, acc[fn], 0,0,0);
                acc[fn] = __builtin_amdgcn_mfma_f32_16x16x32_bf16(A1, B1, acc[fn], 0,0,0);
            }
        }

        #pragma unroll
        for (int fn = 0; fn < 2; ++fn) {
            int o = 16*fn + l15;
            float vals[4];
            #pragma unroll
            for (int r = 0; r < 4; ++r) {
                float v = acc[fn][r];
                if (o < 18) {
                    v += off_b[o];
                    int k = o >> 1;
                    if ((o & 1) == 0) v += (float)(h - 1 + k/3);
                    else              v += (float)(x0 + 4*l4 + r - 1 + (k - (k/3)*3));
                } else if (o < 27) {
                    v = 2.f / (1.f + __expf(-(v + mod_b[o - 18])));
                }
                vals[r] = v;
            }
            if (o < 27)
                *(f32x4*)(coords + (size_t)o * NPX + px0 + 4*l4) =
                    (f32x4){vals[0], vals[1], vals[2], vals[3]};
        }
    }
}

// ---------------- K3: gather + einsum, A-tile shared via LDS ----------------
// 512 blocks x 512 threads (8 waves). Block = 2 output rows (256 px), one img.
// LDS: window 6 rows x 128 px x 144B (110,592) + A-tile 256 px x 144B (36,864).
// Per kk: waves lerp their 32-px slice -> A-tile in LDS; barrier; each wave
// owns couts 16*wv..+15: 2 B-frags from global (issued pre-barrier, drained
// by it) + 32 ds_read A-frags + 32 MFMA; barrier. B traffic = Wb once/block
// (16x less than round 5). Epilogue via LDS transpose -> full-line stores.
__global__ __launch_bounds__(512, 2) void gather_einsum(
        const unsigned short* __restrict__ xp,
        const unsigned short* __restrict__ Wb,
        const float* __restrict__ coords,
        float* __restrict__ out)
{
    __shared__ char smem[147456];
    unsigned short* win = (unsigned short*)smem;            // [6][128] pitch 144B
    unsigned short* At  = (unsigned short*)(smem + 110592); // [256] pitch 144B
    float* epi = (float*)smem;                              // [128][260] f32

    const int tid  = (int)threadIdx.x;
    const int lane = tid & 63;
    const int wv   = tid >> 6;       // 0..7
    const int l15  = lane & 15;
    const int l4   = lane >> 4;

    int bid = (int)blockIdx.x;
    int bswz = (bid & 7) * 64 + (bid >> 3);   // image = bid&7 (512%8==0)
    const int b  = bswz >> 6;
    const int h0 = (bswz & 63) * 2;           // first of 2 output rows

    const unsigned short* xpb = xp + (size_t)b * HWC * CINC;

    // ---- stage window: rows h0-2 .. h0+3 (6 rows) ----
    #pragma unroll
    for (int i = 0; i < 12; ++i) {
        int c = i * 512 + tid;            // 0..6143 16B-chunks
        int r = c >> 10;                  // window row 0..5
        int c10 = c & 1023;
        int xph = c10 >> 3, g = c10 & 7;  // px in row, chunk
        int y = h0 - 2 + r;
        uint4 v = make_uint4(0u,0u,0u,0u);
        if ((unsigned)y < 128u)
            v = *(const uint4*)(xpb + ((size_t)y * 128 + xph) * 64 + g * 8);
        *(uint4*)((char*)win + ((r * 128 + xph) * 144 + g * 16)) = v;
    }

    // ---- per-wave coords for its 32-px lerp slice ----
    const int cbase = b * HWC + h0 * 128 + wv * 32;
    float cy[2][9], cx[2][9], cm[2][9];
    #pragma unroll
    for (int j = 0; j < 2; ++j) {
        int pxl = cbase + j * 16 + l15;
        #pragma unroll
        for (int kk = 0; kk < 9; ++kk) {
            cy[j][kk] = coords[(size_t)(2*kk    ) * NPX + pxl];
            cx[j][kk] = coords[(size_t)(2*kk + 1) * NPX + pxl];
            cm[j][kk] = coords[(size_t)(18 + kk ) * NPX + pxl];
        }
    }
    __syncthreads();

    f32x4 acc[16];
    #pragma unroll
    for (int j2 = 0; j2 < 16; ++j2) acc[j2] = (f32x4){0.f,0.f,0.f,0.f};

    const unsigned short* wrow = Wb + (size_t)(16*wv + l15) * KDIM + 8*l4;

    #pragma unroll
    for (int kk = 0; kk < 9; ++kk) {
        // B-frags for this kk (this wave's cout slice); drain at the barrier
        bf16x8 B0 = *(const bf16x8*)(wrow + kk*64);
        bf16x8 B1 = *(const bf16x8*)(wrow + kk*64 + 32);

        // ---- lerp phase: 2 subtiles of 16 px -> A-tile ----
        #pragma unroll
        for (int j = 0; j < 2; ++j) {
            float Y = cy[j][kk], X = cx[j][kk], m = cm[j][kk];
            float yf = floorf(Y), xf = floorf(X);
            float wy = Y - yf, wx = X - xf;
            int y0 = (int)yf, x0i = (int)xf;
            int y1 = y0 + 1, x1 = x0i + 1;
            bool yv0 = (unsigned)y0 < 128u, yv1 = (unsigned)y1 < 128u;
            bool xv0 = (unsigned)x0i < 128u, xv1 = (unsigned)x1 < 128u;
            int xc0 = x0i < 0 ? 0 : (x0i > 127 ? 127 : x0i);
            int xc1 = x1  < 0 ? 0 : (x1  > 127 ? 127 : x1);
            int wr0 = y0 - (h0 - 2), wr1 = wr0 + 1;
            int wc0 = wr0 < 0 ? 0 : (wr0 > 5 ? 5 : wr0);
            int wc1 = wr1 < 0 ? 0 : (wr1 > 5 ? 5 : wr1);

            const char* r00 = (const char*)win + ((wc0*128 + xc0)*144 + l4*16);
            const char* r01 = (const char*)win + ((wc0*128 + xc1)*144 + l4*16);
            const char* r10 = (const char*)win + ((wc1*128 + xc0)*144 + l4*16);
            const char* r11 = (const char*)win + ((wc1*128 + xc1)*144 + l4*16);
            uint4 cb0 = *(const uint4*)(r00);      uint4 cb1 = *(const uint4*)(r00 + 64);
            uint4 cb2 = *(const uint4*)(r01);      uint4 cb3 = *(const uint4*)(r01 + 64);
            uint4 cb4 = *(const uint4*)(r10);      uint4 cb5 = *(const uint4*)(r10 + 64);
            uint4 cb6 = *(const uint4*)(r11);      uint4 cb7 = *(const uint4*)(r11 + 64);

            // rare fallback: inside image but outside 6-row window
            bool oob = (yv0 && (unsigned)wr0 > 5u) || (yv1 && (unsigned)wr1 > 5u);
            if (__builtin_expect(oob, 0)) {
                int yc0 = y0 < 0 ? 0 : (y0 > 127 ? 127 : y0);
                int yc1 = y1 < 0 ? 0 : (y1 > 127 ? 127 : y1);
                const unsigned short* p00 = xpb + (size_t)(yc0*128 + xc0)*64 + 8*l4;
                const unsigned short* p01 = xpb + (size_t)(yc0*128 + xc1)*64 + 8*l4;
                const unsigned short* p10 = xpb + (size_t)(yc1*128 + xc0)*64 + 8*l4;
                const unsigned short* p11 = xpb + (size_t)(yc1*128 + xc1)*64 + 8*l4;
                cb0 = *(const uint4*)(p00);  cb1 = *(const uint4*)(p00 + 32);
                cb2 = *(const uint4*)(p01);  cb3 = *(const uint4*)(p01 + 32);
                cb4 = *(const uint4*)(p10);  cb5 = *(const uint4*)(p10 + 32);
                cb6 = *(const uint4*)(p11);  cb7 = *(const uint4*)(p11 + 32);
            }

            float u00 = (1.f - wy) * (1.f - wx) * m * ((yv0 && xv0) ? 1.f : 0.f);
            float u01 = (1.f - wy) * wx         * m * ((yv0 && xv1) ? 1.f : 0.f);
            float u10 = wy * (1.f - wx)         * m * ((yv1 && xv0) ? 1.f : 0.f);
            float u11 = wy * wx                 * m * ((yv1 && xv1) ? 1.f : 0.f);

            unsigned pk0[4], pk1[4];
            #pragma unroll
            for (int d = 0; d < 4; ++d) {
                unsigned q00, q01, q10, q11;
                q00 = cb0[d]; q01 = cb2[d]; q10 = cb4[d]; q11 = cb6[d];
                {
                    float slo = bf_lo(q00)*u00 + bf_lo(q01)*u01 + bf_lo(q10)*u10 + bf_lo(q11)*u11;
                    float shi = bf_hi(q00)*u00 + bf_hi(q01)*u01 + bf_hi(q10)*u10 + bf_hi(q11)*u11;
                    pk0[d] = cvtpk(slo, shi);
                }
                q00 = cb1[d]; q01 = cb3[d]; q10 = cb5[d]; q11 = cb7[d];
                {
                    float slo = bf_lo(q00)*u00 + bf_lo(q01)*u01 + bf_lo(q10)*u10 + bf_lo(q11)*u11;
                    float shi = bf_hi(q00)*u00 + bf_hi(q01)*u01 + bf_hi(q10)*u10 + bf_hi(q11)*u11;
                    pk1[d] = cvtpk(slo, shi);
                }
            }
            int px = wv*32 + j*16 + l15;
            *(uint4*)((char*)At + px*144 + l4*16)      = make_uint4(pk0[0], pk0[1], pk0[2], pk0[3]);
            *(uint4*)((char*)At + px*144 + 64 + l4*16) = make_uint4(pk1[0], pk1[1], pk1[2], pk1[3]);
        }
        __syncthreads();

        // ---- GEMM phase: this wave's cout slice x all 256 px ----
        #pragma unroll
        for (int j2 = 0; j2 < 16; ++j2) {
            const char* ar = (const char*)At + (16*j2 + l15)*144 + l4*16;
            bf16x8 A0 = *(const bf16x8*)(ar);
            bf16x8 A1 = *(const bf16x8*)(ar + 64);
            acc[j2] = __builtin_amdgcn_mfma_f32_16x16x32_bf16(A0, B0, acc[j2], 0,0,0);
            acc[j2] = __builtin_amdgcn_mfma_f32_16x16x32_bf16(A1, B1, acc[j2], 0,0,0);
        }
        __syncthreads();
    }

    // ---- epilogue: acc -> LDS [cout][px] (pitch 260 f32) -> full-line stores
    #pragma unroll
    for (int j2 = 0; j2 < 16; ++j2)
        *(f32x4*)(epi + (size_t)(16*wv + l15) * 260 + 16*j2 + 4*l4) = acc[j2];
    __syncthreads();

    float* ob = out + (size_t)b * COUTC * HWC + h0 * 128 + (tid & 63) * 4;
    #pragma unroll
    for (int it = 0; it < 16; ++it) {
        int o = it * 8 + (tid >> 6);
        f32x4 v = *(const f32x4*)(epi + (size_t)o * 260 + (tid & 63) * 4);
        *(f32x4*)(ob + (size_t)o * HWC) = v;
    }
}

extern "C" void kernel_launch(void* const* d_in, const int* in_sizes, int n_in,
                              void* d_out, int out_size, void* d_ws, size_t ws_size,
                              hipStream_t stream)
{
    const float* x     = (const float*)d_in[0];
    const float* pre_w = (const float*)d_in[1];
    const float* pre_b = (const float*)d_in[2];
    const float* off_w = (const float*)d_in[3];
    const float* off_b = (const float*)d_in[4];
    const float* mod_w = (const float*)d_in[5];
    const float* mod_b = (const float*)d_in[6];
    const float* reg_w = (const float*)d_in[7];
    float* out = (float*)d_out;

    unsigned short* xp = (unsigned short*)d_ws;                                 // 16,777,216 B
    unsigned short* Wb = (unsigned short*)((char*)d_ws + 16777216);             //    147,456 B
    unsigned short* Wc = (unsigned short*)((char*)d_ws + 16777216 + 147456);    //     36,864 B
    float* coords = (float*)((char*)d_ws + 16777216 + 147456 + 36864);          // 16,777,216 B

    prep_weights<<<dim3(360),  dim3(256), 0, stream>>>(off_w, mod_w, reg_w, Wb, Wc);
    conv1x1    <<<dim3(512),  dim3(256), 0, stream>>>(x, pre_w, pre_b, xp);
    offset_conv<<<dim3(1024), dim3(256), 0, stream>>>(xp, Wc, off_b, mod_b, coords);
    gather_einsum<<<dim3(512), dim3(512), 0, stream>>>(xp, Wb, coords, out);
}

// Round 7
// 105.912 us; speedup vs baseline: 6.5020x; 1.3123x over previous
//
#include <hip/hip_runtime.h>
#include <hip/hip_bf16.h>
#include <cstdint>
#include <cstddef>

#define BATCH 8
#define CINC  64
#define HH    128
#define WWW   128
#define COUTC 128
#define KKC   9
#define KDIM  576   // KK*CIN, k = kk*64 + c
#define HWC   (HH*WWW)      // 16384
#define NPX   (BATCH*HWC)   // 131072

typedef float f32x4 __attribute__((ext_vector_type(4)));
typedef short bf16x8 __attribute__((ext_vector_type(8)));

static __device__ __forceinline__ unsigned short f2bf(float f){
    unsigned u = __builtin_bit_cast(unsigned, f);
    u += 0x7fffu + ((u >> 16) & 1u);
    return (unsigned short)(u >> 16);
}
static __device__ __forceinline__ float bf_lo(unsigned u){
    return __builtin_bit_cast(float, u << 16);
}
static __device__ __forceinline__ float bf_hi(unsigned u){
    return __builtin_bit_cast(float, u & 0xffff0000u);
}
static __device__ __forceinline__ unsigned cvtpk(float lo, float hi){
    unsigned r;
    asm("v_cvt_pk_bf16_f32 %0, %1, %2" : "=v"(r) : "v"(lo), "v"(hi));
    return r;
}

// ---------------- K0: pack weights to bf16 ---------------------------------
// Wb[o][k], Wc[o][k] with k = kk*64+c; Wp[o][ci] for the 1x1 conv.
__global__ __launch_bounds__(256) void prep_weights(
        const float* __restrict__ off_w, const float* __restrict__ mod_w,
        const float* __restrict__ reg_w, const float* __restrict__ pre_w,
        unsigned short* __restrict__ Wb, unsigned short* __restrict__ Wc,
        unsigned short* __restrict__ Wp)
{
    int idx = blockIdx.x * 256 + threadIdx.x;
    if (idx < COUTC * KDIM) {
        int o = idx / KDIM, k = idx % KDIM;
        int kk = k >> 6, c = k & 63;
        Wb[idx] = f2bf(reg_w[(o * CINC + c) * KKC + kk]);
    }
    int idx2 = idx - COUTC * KDIM;
    if (idx2 >= 0 && idx2 < 32 * KDIM) {
        int o = idx2 / KDIM, k = idx2 % KDIM;
        int kk = k >> 6, c = k & 63;
        float v = 0.f;
        if (o < 18)      v = off_w[(o * CINC + c) * KKC + kk];      // o = kk*2+d
        else if (o < 27) v = mod_w[((o - 18) * CINC + c) * KKC + kk];
        Wc[idx2] = f2bf(v);
    }
    int idx3 = idx - (COUTC * KDIM + 32 * KDIM);
    if (idx3 >= 0 && idx3 < CINC * CINC)
        Wp[idx3] = f2bf(pre_w[idx3]);
}

// ---------------- K1: 1x1 conv via MFMA, NCHW f32 -> NHWC bf16 --------------
// 512 blocks x 256 thr (4 waves). Wave = 64 px x 64 co, K=64.
// A = x (f32 coalesced 64B-segment loads -> cvt_pk bf16), B = Wp regs.
// Epilogue: per-wave LDS slab transpose (no barrier) -> 128B/px stores.
__global__ __launch_bounds__(256) void conv1x1(
        const float* __restrict__ x, const unsigned short* __restrict__ Wp,
        const float* __restrict__ pre_b, unsigned short* __restrict__ xp)
{
    __shared__ unsigned short slab[4][64 * 72];   // 9216 B per wave

    const int tid = threadIdx.x;
    const int lane = tid & 63;
    const int wv   = tid >> 6;
    const int l15  = lane & 15;
    const int l4   = lane >> 4;

    int bid = (int)blockIdx.x;
    int bswz = (bid & 7) * 64 + (bid >> 3);   // image = bid&7
    int pxb = bswz * 256 + wv * 64;           // wave's 64 px
    int b = pxb >> 14, hw0 = pxb & 16383;
    const float* xb = x + (size_t)b * CINC * HWC + hw0;

    // B-frags (co = 16*fn+l15, ci = 32*s + 8*l4 ..+7)
    bf16x8 bw[4][2];
    #pragma unroll
    for (int fn = 0; fn < 4; ++fn)
        #pragma unroll
        for (int s = 0; s < 2; ++s)
            bw[fn][s] = *(const bf16x8*)(Wp + (size_t)(16*fn + l15) * 64 + 32*s + 8*l4);
    float pb[4];
    #pragma unroll
    for (int fn = 0; fn < 4; ++fn) pb[fn] = pre_b[16*fn + l15];

    f32x4 acc[4][4];
    #pragma unroll
    for (int su = 0; su < 4; ++su)
        #pragma unroll
        for (int fn = 0; fn < 4; ++fn) acc[su][fn] = (f32x4){0.f,0.f,0.f,0.f};

    #pragma unroll
    for (int su = 0; su < 4; ++su) {
        #pragma unroll
        for (int s = 0; s < 2; ++s) {
            float f[8];
            #pragma unroll
            for (int j = 0; j < 8; ++j)
                f[j] = xb[(size_t)(s*32 + 8*l4 + j) * HWC + su*16 + l15];
            unsigned pk[4];
            #pragma unroll
            for (int d = 0; d < 4; ++d) pk[d] = cvtpk(f[2*d], f[2*d+1]);
            bf16x8 A = __builtin_bit_cast(bf16x8, make_uint4(pk[0], pk[1], pk[2], pk[3]));
            #pragma unroll
            for (int fn = 0; fn < 4; ++fn)
                acc[su][fn] = __builtin_amdgcn_mfma_f32_16x16x32_bf16(A, bw[fn][s], acc[su][fn], 0,0,0);
        }
    }

    // epilogue: lane holds co = 16fn+l15, px-row = su*16 + 4*l4 + r
    unsigned short* sl = slab[wv];
    #pragma unroll
    for (int su = 0; su < 4; ++su)
        #pragma unroll
        for (int fn = 0; fn < 4; ++fn)
            #pragma unroll
            for (int r = 0; r < 4; ++r)
                sl[(su*16 + 4*l4 + r) * 72 + 16*fn + l15] = f2bf(acc[su][fn][r] + pb[fn]);
    // same-wave LDS write->read: in-order, compiler inserts waits
    const uint4* srow = (const uint4*)(sl + lane * 72);
    uint4* drow = (uint4*)(xp + (size_t)(pxb + lane) * 64);
    #pragma unroll
    for (int q = 0; q < 8; ++q) drow[q] = srow[q];
}

// ---------------- K3: fused offset-conv + gather + einsum -------------------
// 512 blocks x 512 threads (8 waves). Block = 2 output rows (256 px), one img.
// LDS: window 6 rows x 128 px x 144B (110,592) + At 256 px x 144B (36,864).
// Phases: stage window -> offset/mask conv from window (Dt transpose in At
// area) -> coords to regs -> per-kk {lerp -> At; barrier; GEMM; barrier} ->
// epilogue via LDS transpose. GEMM tiling: 8 waves = 2(M=128px) x 4(N=32co).
__global__ __launch_bounds__(512, 2) void gather_einsum(
        const unsigned short* __restrict__ xp,
        const unsigned short* __restrict__ Wb,
        const unsigned short* __restrict__ Wc,
        const float* __restrict__ off_b,
        const float* __restrict__ mod_b,
        float* __restrict__ out)
{
    __shared__ char smem[147456];
    unsigned short* win = (unsigned short*)smem;            // [6][128] pitch 144B
    unsigned short* At  = (unsigned short*)(smem + 110592); // [256] pitch 144B
    float* epi = (float*)smem;                              // [128][260] f32

    const int tid  = (int)threadIdx.x;
    const int lane = tid & 63;
    const int wv   = tid >> 6;       // 0..7
    const int l15  = lane & 15;
    const int l4   = lane >> 4;

    int bid = (int)blockIdx.x;
    int bswz = (bid & 7) * 64 + (bid >> 3);   // image = bid&7 (512%8==0)
    const int b  = bswz >> 6;
    const int h0 = (bswz & 63) * 2;           // first of 2 output rows

    const unsigned short* xpb = xp + (size_t)b * HWC * CINC;

    // ---- stage window: rows h0-2 .. h0+3 (6 rows) ----
    #pragma unroll
    for (int i = 0; i < 12; ++i) {
        int c = i * 512 + tid;            // 0..6143 16B-chunks
        int r = c >> 10;                  // window row 0..5
        int c10 = c & 1023;
        int xph = c10 >> 3, g = c10 & 7;  // px in row, chunk
        int y = h0 - 2 + r;
        uint4 v = make_uint4(0u,0u,0u,0u);
        if ((unsigned)y < 128u)
            v = *(const uint4*)(xpb + ((size_t)y * 128 + xph) * 64 + g * 8);
        *(uint4*)((char*)win + ((r * 128 + xph) * 144 + g * 16)) = v;
    }
    __syncthreads();

    // ---- Phase O: offset/mask conv from window ----
    const int hrow = wv >> 2;           // output row within block
    const int x0w  = (wv & 3) * 32;     // x of this wave's 32-px slice
    {
        f32x4 aco[2][2];                // [j][fn]
        #pragma unroll
        for (int j = 0; j < 2; ++j)
            #pragma unroll
            for (int fn = 0; fn < 2; ++fn) aco[j][fn] = (f32x4){0.f,0.f,0.f,0.f};

        bf16x8 bc0[2], bc1[2];          // B(kk) frags, [fn] x chunk s
        #pragma unroll
        for (int fn = 0; fn < 2; ++fn) {
            bc0[fn] = *(const bf16x8*)(Wc + (size_t)(16*fn + l15) * KDIM + 8*l4);
            bc1[fn] = *(const bf16x8*)(Wc + (size_t)(16*fn + l15) * KDIM + 32 + 8*l4);
        }
        #pragma unroll
        for (int kk = 0; kk < 9; ++kk) {
            bf16x8 bn0[2], bn1[2];
            if (kk < 8) {
                #pragma unroll
                for (int fn = 0; fn < 2; ++fn) {
                    bn0[fn] = *(const bf16x8*)(Wc + (size_t)(16*fn + l15) * KDIM + (kk+1)*64 + 8*l4);
                    bn1[fn] = *(const bf16x8*)(Wc + (size_t)(16*fn + l15) * KDIM + (kk+1)*64 + 32 + 8*l4);
                }
            }
            int wr_ = hrow + (kk / 3) + 1;     // window row: y = h0+hrow+kk/3-1
            #pragma unroll
            for (int j = 0; j < 2; ++j) {
                int xx = x0w + j*16 + l15 + (kk % 3) - 1;
                bool xv = (unsigned)xx < 128u;
                int xc = xx < 0 ? 0 : (xx > 127 ? 127 : xx);
                const char* rr = (const char*)win + ((wr_*128 + xc)*144 + l4*16);
                uint4 a0 = *(const uint4*)(rr);
                uint4 a1 = *(const uint4*)(rr + 64);
                if (!xv) { a0 = make_uint4(0,0,0,0); a1 = make_uint4(0,0,0,0); }
                bf16x8 A0 = __builtin_bit_cast(bf16x8, a0);
                bf16x8 A1 = __builtin_bit_cast(bf16x8, a1);
                #pragma unroll
                for (int fn = 0; fn < 2; ++fn) {
                    aco[j][fn] = __builtin_amdgcn_mfma_f32_16x16x32_bf16(A0, bc0[fn], aco[j][fn], 0,0,0);
                    aco[j][fn] = __builtin_amdgcn_mfma_f32_16x16x32_bf16(A1, bc1[fn], aco[j][fn], 0,0,0);
                }
            }
            #pragma unroll
            for (int fn = 0; fn < 2; ++fn) { bc0[fn] = bn0[fn]; bc1[fn] = bn1[fn]; }
        }
        // epilogue-O: D -> Dt[px][o] (f32, pitch 33 words) in the At area
        float* Dt = (float*)At;
        #pragma unroll
        for (int j = 0; j < 2; ++j)
        #pragma unroll
        for (int fn = 0; fn < 2; ++fn) {
            int o = 16*fn + l15;
            #pragma unroll
            for (int r = 0; r < 4; ++r) {
                int pr = 4*l4 + r;
                int px = wv*32 + j*16 + pr;
                float v = aco[j][fn][r];
                if (o < 18) {
                    v += off_b[o];
                    int k = o >> 1;
                    if ((o & 1) == 0) v += (float)(h0 + hrow - 1 + k/3);
                    else              v += (float)(x0w + j*16 + pr - 1 + (k % 3));
                } else if (o < 27) {
                    v = 2.f / (1.f + __expf(-(v + mod_b[o - 18])));
                }
                if (o < 27) Dt[px*33 + o] = v;
            }
        }
    }
    __syncthreads();

    // ---- Phase C: coords -> regs ----
    float cy[2][9], cx[2][9], cm[2][9];
    {
        const float* Dt = (const float*)At;
        #pragma unroll
        for (int j = 0; j < 2; ++j) {
            int px = wv*32 + j*16 + l15;
            #pragma unroll
            for (int kk = 0; kk < 9; ++kk) {
                cy[j][kk] = Dt[px*33 + 2*kk];
                cx[j][kk] = Dt[px*33 + 2*kk + 1];
                cm[j][kk] = Dt[px*33 + 18 + kk];
            }
        }
    }
    __syncthreads();   // all coords read before lerp overwrites At

    // ---- main loop ----
    f32x4 acc[8][2];
    #pragma unroll
    for (int m = 0; m < 8; ++m) { acc[m][0] = (f32x4){0.f,0.f,0.f,0.f};
                                  acc[m][1] = (f32x4){0.f,0.f,0.f,0.f}; }

    const int wr = wv >> 2, wc = wv & 3;
    const unsigned short* wrow = Wb + (size_t)(32*wc + l15) * KDIM + 8*l4;

    #pragma unroll
    for (int kk = 0; kk < 9; ++kk) {
        // B-frags for this kk (wave's 32-cout slice); lerp hides the latency
        bf16x8 Bf[2][2];
        #pragma unroll
        for (int f = 0; f < 2; ++f) {
            Bf[f][0] = *(const bf16x8*)(wrow + (size_t)f*16*KDIM + kk*64);
            Bf[f][1] = *(const bf16x8*)(wrow + (size_t)f*16*KDIM + kk*64 + 32);
        }

        // ---- lerp: 2 subtiles of 16 px -> A-tile ----
        #pragma unroll
        for (int j = 0; j < 2; ++j) {
            float Y = cy[j][kk], X = cx[j][kk], m = cm[j][kk];
            float yf = floorf(Y), xf = floorf(X);
            float wy = Y - yf, wx = X - xf;
            int y0 = (int)yf, x0i = (int)xf;
            int y1 = y0 + 1, x1 = x0i + 1;
            bool yv0 = (unsigned)y0 < 128u, yv1 = (unsigned)y1 < 128u;
            bool xv0 = (unsigned)x0i < 128u, xv1 = (unsigned)x1 < 128u;
            int xc0 = x0i < 0 ? 0 : (x0i > 127 ? 127 : x0i);
            int xc1 = x1  < 0 ? 0 : (x1  > 127 ? 127 : x1);
            int wr0 = y0 - (h0 - 2), wr1 = wr0 + 1;
            int wc0 = wr0 < 0 ? 0 : (wr0 > 5 ? 5 : wr0);
            int wc1 = wr1 < 0 ? 0 : (wr1 > 5 ? 5 : wr1);

            const char* r00 = (const char*)win + ((wc0*128 + xc0)*144 + l4*16);
            const char* r01 = (const char*)win + ((wc0*128 + xc1)*144 + l4*16);
            const char* r10 = (const char*)win + ((wc1*128 + xc0)*144 + l4*16);
            const char* r11 = (const char*)win + ((wc1*128 + xc1)*144 + l4*16);
            uint4 cb0 = *(const uint4*)(r00);      uint4 cb1 = *(const uint4*)(r00 + 64);
            uint4 cb2 = *(const uint4*)(r01);      uint4 cb3 = *(const uint4*)(r01 + 64);
            uint4 cb4 = *(const uint4*)(r10);      uint4 cb5 = *(const uint4*)(r10 + 64);
            uint4 cb6 = *(const uint4*)(r11);      uint4 cb7 = *(const uint4*)(r11 + 64);

            // rare fallback: inside image but outside 6-row window
            bool oob = (yv0 && (unsigned)wr0 > 5u) || (yv1 && (unsigned)wr1 > 5u);
            if (__builtin_expect(oob, 0)) {
                int yc0 = y0 < 0 ? 0 : (y0 > 127 ? 127 : y0);
                int yc1 = y1 < 0 ? 0 : (y1 > 127 ? 127 : y1);
                const unsigned short* p00 = xpb + (size_t)(yc0*128 + xc0)*64 + 8*l4;
                const unsigned short* p01 = xpb + (size_t)(yc0*128 + xc1)*64 + 8*l4;
                const unsigned short* p10 = xpb + (size_t)(yc1*128 + xc0)*64 + 8*l4;
                const unsigned short* p11 = xpb + (size_t)(yc1*128 + xc1)*64 + 8*l4;
                cb0 = *(const uint4*)(p00);  cb1 = *(const uint4*)(p00 + 32);
                cb2 = *(const uint4*)(p01);  cb3 = *(const uint4*)(p01 + 32);
                cb4 = *(const uint4*)(p10);  cb5 = *(const uint4*)(p10 + 32);
                cb6 = *(const uint4*)(p11);  cb7 = *(const uint4*)(p11 + 32);
            }

            float u00 = (1.f - wy) * (1.f - wx) * m * ((yv0 && xv0) ? 1.f : 0.f);
            float u01 = (1.f - wy) * wx         * m * ((yv0 && xv1) ? 1.f : 0.f);
            float u10 = wy * (1.f - wx)         * m * ((yv1 && xv0) ? 1.f : 0.f);
            float u11 = wy * wx                 * m * ((yv1 && xv1) ? 1.f : 0.f);

            unsigned pk0[4], pk1[4];
            #pragma unroll
            for (int d = 0; d < 4; ++d) {
                unsigned q00, q01, q10, q11;
                q00 = cb0[d]; q01 = cb2[d]; q10 = cb4[d]; q11 = cb6[d];
                {
                    float slo = bf_lo(q00)*u00 + bf_lo(q01)*u01 + bf_lo(q10)*u10 + bf_lo(q11)*u11;
                    float shi = bf_hi(q00)*u00 + bf_hi(q01)*u01 + bf_hi(q10)*u10 + bf_hi(q11)*u11;
                    pk0[d] = cvtpk(slo, shi);
                }
                q00 = cb1[d]; q01 = cb3[d]; q10 = cb5[d]; q11 = cb7[d];
                {
                    float slo = bf_lo(q00)*u00 + bf_lo(q01)*u01 + bf_lo(q10)*u10 + bf_lo(q11)*u11;
                    float shi = bf_hi(q00)*u00 + bf_hi(q01)*u01 + bf_hi(q10)*u10 + bf_hi(q11)*u11;
                    pk1[d] = cvtpk(slo, shi);
                }
            }
            int px = wv*32 + j*16 + l15;
            *(uint4*)((char*)At + px*144 + l4*16)      = make_uint4(pk0[0], pk0[1], pk0[2], pk0[3]);
            *(uint4*)((char*)At + px*144 + 64 + l4*16) = make_uint4(pk1[0], pk1[1], pk1[2], pk1[3]);
        }
        __syncthreads();

        // ---- GEMM: wave's 128-px x 32-cout tile ----
        #pragma unroll
        for (int m = 0; m < 8; ++m) {
            const char* ar = (const char*)At + (128*wr + 16*m + l15)*144 + l4*16;
            bf16x8 A0 = *(const bf16x8*)(ar);
            bf16x8 A1 = *(const bf16x8*)(ar + 64);
            acc[m][0] = __builtin_amdgcn_mfma_f32_16x16x32_bf16(A0, Bf[0][0], acc[m][0], 0,0,0);
            acc[m][0] = __builtin_amdgcn_mfma_f32_16x16x32_bf16(A1, Bf[0][1], acc[m][0], 0,0,0);
            acc[m][1] = __builtin_amdgcn_mfma_f32_16x16x32_bf16(A0, Bf[1][0], acc[m][1], 0,0,0);
            acc[m][1] = __builtin_amdgcn_mfma_f32_16x16x32_bf16(A1, Bf[1][1], acc[m][1], 0,0,0);
        }
        __syncthreads();
    }

    // ---- epilogue: acc -> LDS [cout][px] (pitch 260 f32) -> full-line stores
    #pragma unroll
    for (int m = 0; m < 8; ++m)
        #pragma unroll
        for (int f = 0; f < 2; ++f)
            *(f32x4*)(epi + (size_t)(32*wc + 16*f + l15) * 260 + 128*wr + 16*m + 4*l4) = acc[m][f];
    __syncthreads();

    float* ob = out + (size_t)b * COUTC * HWC + h0 * 128 + (tid & 63) * 4;
    #pragma unroll
    for (int it = 0; it < 16; ++it) {
        int o = it * 8 + (tid >> 6);
        f32x4 v = *(const f32x4*)(epi + (size_t)o * 260 + (tid & 63) * 4);
        *(f32x4*)(ob + (size_t)o * HWC) = v;
    }
}

extern "C" void kernel_launch(void* const* d_in, const int* in_sizes, int n_in,
                              void* d_out, int out_size, void* d_ws, size_t ws_size,
                              hipStream_t stream)
{
    const float* x     = (const float*)d_in[0];
    const float* pre_w = (const float*)d_in[1];
    const float* pre_b = (const float*)d_in[2];
    const float* off_w = (const float*)d_in[3];
    const float* off_b = (const float*)d_in[4];
    const float* mod_w = (const float*)d_in[5];
    const float* mod_b = (const float*)d_in[6];
    const float* reg_w = (const float*)d_in[7];
    float* out = (float*)d_out;

    unsigned short* xp = (unsigned short*)d_ws;                              // 16,777,216 B
    unsigned short* Wb = (unsigned short*)((char*)d_ws + 16777216);          //    147,456 B
    unsigned short* Wc = (unsigned short*)((char*)d_ws + 16924672);          //     36,864 B
    unsigned short* Wp = (unsigned short*)((char*)d_ws + 16961536);          //      8,192 B

    prep_weights<<<dim3(376), dim3(256), 0, stream>>>(off_w, mod_w, reg_w, pre_w, Wb, Wc, Wp);
    conv1x1     <<<dim3(512), dim3(256), 0, stream>>>(x, Wp, pre_b, xp);
    gather_einsum<<<dim3(512), dim3(512), 0, stream>>>(xp, Wb, Wc, off_b, mod_b, out);
}